// Round 3
// baseline (167.651 us; speedup 1.0000x reference)
//
#include <hip/hip_runtime.h>
#include <stdint.h>

// Problem dims
#define T_HRZ 1024
#define NBAT  128
#define NHID  256
#define NPAIR 128
#define NUIN  64
#define NYOUT 64
#define LCH   16   // chunk length
#define CCH   64   // number of chunks

// Workspace layout (float offsets). Total ~4.24M floats = 17 MB.
#define WS_LAM   0         // lr[128], li[128]
#define WS_LAML  256       // lambda^16 r[128], i[128]
#define WS_X0P   512       // x0 pair-interleaved [b][j][2] : 128*128*2
#define WS_WBU   33280     // bf16 B-frags for Bu GEMM [nt16][kk2][lane64][j8] : 8192 floats
#define WS_WBY   41472     // bf16 B-frags for Y GEMM  [nt4][kk8][lane64][j8] : 8192 floats
#define WS_S     49664     // chunk sums [c][b][j] float2 : 2097152
#define WS_E     2146816   // entry states [c][b][j] float2 : 2097152

typedef __attribute__((ext_vector_type(8))) short short8;
typedef __attribute__((ext_vector_type(4))) float float4v;

__device__ __forceinline__ unsigned int f2bf_bits(float x) {
  unsigned int u = __float_as_uint(x);
  return (u + 0x7fffu + ((u >> 16) & 1u)) >> 16;  // RNE
}

// ---------------------------------------------------------------------------
// K1: prep. grid (NBAT+3) x 256.
//  blocks 0..127 : x0[b] = y0[b] @ W_y2x^T + b_y2x (pair-interleaved)
//  block 128     : lambda, lambda^16
//  block 129     : WBU bf16 fragment layout of BnfT[u][h] = B[h][u]*nf[h]
//  block 130     : WBY bf16 fragment layout of WT[h][y]   = W_x2y[y][h]
// ---------------------------------------------------------------------------
__global__ __launch_bounds__(256) void k_prep(
    const float* __restrict__ y0, const float* __restrict__ lrc,
    const float* __restrict__ lic, const float* __restrict__ Bm,
    const float* __restrict__ Wy2x, const float* __restrict__ by2x,
    const float* __restrict__ Wx2y, float* __restrict__ ws)
{
  int blk = blockIdx.x;
  int h = threadIdx.x;  // 0..255
  if (blk < NBAT) {
    __shared__ float y0s[NYOUT];
    if (h < NYOUT) y0s[h] = y0[blk * NYOUT + h];
    __syncthreads();
    float acc = by2x[h];
    const float* wr = Wy2x + h * NYOUT;
#pragma unroll 16
    for (int k = 0; k < NYOUT; ++k) acc += y0s[k] * wr[k];
    int j = h & (NPAIR - 1);
    int comp = h >> 7;
    ws[WS_X0P + (blk * NPAIR + j) * 2 + comp] = acc;
  } else if (blk == NBAT) {
    if (h < NPAIR) {
      float a  = fabsf(lrc[h]);
      float r  = expf(-a);
      float th = 1.5707963267948966f * lic[h];
      float lr = r * cosf(th);
      float li = r * sinf(th);
      ws[WS_LAM + h]         = lr;
      ws[WS_LAM + NPAIR + h] = li;
      float pr = lr, pi_ = li;
      for (int l = 1; l < LCH; ++l) {
        float nr = pr * lr - pi_ * li;
        float ni = pr * li + pi_ * lr;
        pr = nr; pi_ = ni;
      }
      ws[WS_LAML + h]         = pr;  // lambda^16
      ws[WS_LAML + NPAIR + h] = pi_;
    }
  } else if (blk == NBAT + 1) {
    unsigned short* wbu = (unsigned short*)(ws + WS_WBU);
    for (int idx = h; idx < 16384; idx += 256) {
      int nt   = idx >> 10;
      int kk   = (idx >> 9) & 1;
      int lane = (idx >> 3) & 63;
      int jj   = idx & 7;
      int u  = kk * 32 + (lane >> 4) * 8 + jj;
      int hh = nt * 16 + (lane & 15);
      float a2 = fabsf(lrc[hh & (NPAIR - 1)]);
      float nf = sqrtf(1.f - expf(-2.f * a2));
      wbu[idx] = (unsigned short)f2bf_bits(Bm[hh * NUIN + u] * nf);
    }
  } else {
    unsigned short* wby = (unsigned short*)(ws + WS_WBY);
    for (int idx = h; idx < 16384; idx += 256) {
      int nt   = idx >> 12;
      int kk   = (idx >> 9) & 7;
      int lane = (idx >> 3) & 63;
      int jj   = idx & 7;
      int hh = kk * 32 + (lane >> 4) * 8 + jj;
      int y  = nt * 16 + (lane & 15);
      wby[idx] = (unsigned short)f2bf_bits(Wx2y[y * NHID + hh]);
    }
  }
}

// ---------------------------------------------------------------------------
// K2: phase A. grid (CCH, NBAT) x 128 (2 waves).
// Bu tile via MFMA, transpose through LDS, weighted scan from zero -> S only.
// ---------------------------------------------------------------------------
__global__ __launch_bounds__(128) void k_phaseA(
    const float* __restrict__ U, float* __restrict__ ws)
{
  int c = blockIdx.x, b = blockIdx.y;
  int tid = threadIdx.x, wave = tid >> 6, lane = tid & 63;
  int m = lane & 15, quad = lane >> 4;
  __shared__ float X32[LCH * 260];   // pitch 260 -> 2-way conflicts only

  // A-frags: U[t=m][u = kk*32 + quad*8 + j]
  const float* urow = U + ((size_t)(c * LCH + m) * NBAT + b) * NUIN;
  short8 afr[2];
#pragma unroll
  for (int kk = 0; kk < 2; ++kk) {
    int u0 = kk * 32 + quad * 8;
    float4 va = *(const float4*)(urow + u0);
    float4 vb = *(const float4*)(urow + u0 + 4);
    short8 f;
    f[0] = (short)f2bf_bits(va.x); f[1] = (short)f2bf_bits(va.y);
    f[2] = (short)f2bf_bits(va.z); f[3] = (short)f2bf_bits(va.w);
    f[4] = (short)f2bf_bits(vb.x); f[5] = (short)f2bf_bits(vb.y);
    f[6] = (short)f2bf_bits(vb.z); f[7] = (short)f2bf_bits(vb.w);
    afr[kk] = f;
  }

  const short8* wbu = (const short8*)(ws + WS_WBU);
  float4v z = {0.f, 0.f, 0.f, 0.f};
  float4v acc[8];
#pragma unroll
  for (int n = 0; n < 8; ++n) acc[n] = z;
#pragma unroll
  for (int n = 0; n < 8; ++n) {
    int nt = wave * 8 + n;
    acc[n] = __builtin_amdgcn_mfma_f32_16x16x32_bf16(afr[0], wbu[(nt * 2 + 0) * 64 + lane], acc[n], 0, 0, 0);
    acc[n] = __builtin_amdgcn_mfma_f32_16x16x32_bf16(afr[1], wbu[(nt * 2 + 1) * 64 + lane], acc[n], 0, 0, 0);
  }

  // C-layout (row=quad*4+r = t, col=lane&15) -> LDS [t][h]
#pragma unroll
  for (int n = 0; n < 8; ++n) {
    int hh = (wave * 8 + n) * 16 + (lane & 15);
#pragma unroll
    for (int r = 0; r < 4; ++r)
      X32[(quad * 4 + r) * 260 + hh] = acc[n][r];
  }
  __syncthreads();

  int j = tid;
  float lr = ws[WS_LAM + j], li = ws[WS_LAM + NPAIR + j];
  float s1 = 0.f, s2 = 0.f;
#pragma unroll
  for (int l = 0; l < LCH; ++l) {
    float v1 = X32[l * 260 + j];
    float v2 = X32[l * 260 + NPAIR + j];
    float n1 = lr * s1 - li * s2 + v1;
    float n2 = li * s1 + lr * s2 + v2;
    s1 = n1; s2 = n2;
  }
  ((float2*)(ws + WS_S))[((size_t)c * NBAT + b) * NPAIR + j] = make_float2(s1, s2);
}

// ---------------------------------------------------------------------------
// K3: phase B. grid NBAT x 128. 64-step chunk scan, 8-way prefetch.
// ---------------------------------------------------------------------------
__global__ __launch_bounds__(128) void k_phaseB(float* __restrict__ ws)
{
  int b = blockIdx.x, j = threadIdx.x;
  float e1 = ws[WS_X0P + (b * NPAIR + j) * 2 + 0];
  float e2 = ws[WS_X0P + (b * NPAIR + j) * 2 + 1];
  float Lr = ws[WS_LAML + j], Li = ws[WS_LAML + NPAIR + j];
  const float2* sp = (const float2*)(ws + WS_S);
  float2* ep = (float2*)(ws + WS_E);
  const size_t cs = (size_t)NBAT * NPAIR;
  size_t o0 = (size_t)b * NPAIR + j;
  float2 buf[8];
#pragma unroll
  for (int k = 0; k < 8; ++k) buf[k] = sp[k * cs + o0];
  for (int g = 0; g < 8; ++g) {
    float2 nxt[8];
    if (g < 7) {
#pragma unroll
      for (int k = 0; k < 8; ++k) nxt[k] = sp[(size_t)((g + 1) * 8 + k) * cs + o0];
    }
#pragma unroll
    for (int k = 0; k < 8; ++k) {
      ep[(size_t)(g * 8 + k) * cs + o0] = make_float2(e1, e2);
      float n1 = Lr * e1 - Li * e2 + buf[k].x;
      float n2 = Li * e1 + Lr * e2 + buf[k].y;
      e1 = n1; e2 = n2;
    }
    if (g < 7) {
#pragma unroll
      for (int k = 0; k < 8; ++k) buf[k] = nxt[k];
    }
  }
}

// ---------------------------------------------------------------------------
// K4: phase C. grid (CCH, NBAT) x 128 (2 waves).
// Recompute Bu via MFMA from raw U (L3-warm), transpose through LDS,
// 16-step fp32 scan seeded from e[c], bf16 X into A-frag LDS, Y-MFMA, bias.
// ---------------------------------------------------------------------------
__global__ __launch_bounds__(128) void k_phaseC(
    const float* __restrict__ U, const float* __restrict__ bx2y,
    float* __restrict__ out, float* __restrict__ ws)
{
  int c = blockIdx.x, b = blockIdx.y;
  int tid = threadIdx.x, wave = tid >> 6, lane = tid & 63;
  int m = lane & 15, quad = lane >> 4;
  __shared__ float X32[LCH * 260];
  __shared__ unsigned short XA[8 * 64 * 8];  // [kk][lane][j] = X[t=lane&15][h=kk*32+(lane>>4)*8+j]

  // --- Bu recompute (same front end as phase A) ---
  const float* urow = U + ((size_t)(c * LCH + m) * NBAT + b) * NUIN;
  short8 afr[2];
#pragma unroll
  for (int kk = 0; kk < 2; ++kk) {
    int u0 = kk * 32 + quad * 8;
    float4 va = *(const float4*)(urow + u0);
    float4 vb = *(const float4*)(urow + u0 + 4);
    short8 f;
    f[0] = (short)f2bf_bits(va.x); f[1] = (short)f2bf_bits(va.y);
    f[2] = (short)f2bf_bits(va.z); f[3] = (short)f2bf_bits(va.w);
    f[4] = (short)f2bf_bits(vb.x); f[5] = (short)f2bf_bits(vb.y);
    f[6] = (short)f2bf_bits(vb.z); f[7] = (short)f2bf_bits(vb.w);
    afr[kk] = f;
  }

  const short8* wbu = (const short8*)(ws + WS_WBU);
  float4v z = {0.f, 0.f, 0.f, 0.f};
  {
    float4v acc[8];
#pragma unroll
    for (int n = 0; n < 8; ++n) acc[n] = z;
#pragma unroll
    for (int n = 0; n < 8; ++n) {
      int nt = wave * 8 + n;
      acc[n] = __builtin_amdgcn_mfma_f32_16x16x32_bf16(afr[0], wbu[(nt * 2 + 0) * 64 + lane], acc[n], 0, 0, 0);
      acc[n] = __builtin_amdgcn_mfma_f32_16x16x32_bf16(afr[1], wbu[(nt * 2 + 1) * 64 + lane], acc[n], 0, 0, 0);
    }
#pragma unroll
    for (int n = 0; n < 8; ++n) {
      int hh = (wave * 8 + n) * 16 + (lane & 15);
#pragma unroll
      for (int r = 0; r < 4; ++r)
        X32[(quad * 4 + r) * 260 + hh] = acc[n][r];
    }
  }
  __syncthreads();

  // --- 16-step fp32 scan from e[c]; write bf16 X in A-frag order ---
  int j = tid;
  float lr = ws[WS_LAM + j], li = ws[WS_LAM + NPAIR + j];
  float2 e = ((const float2*)(ws + WS_E))[((size_t)c * NBAT + b) * NPAIR + j];
  float x1 = e.x, x2 = e.y;
  int h1 = j, h2 = j + NPAIR;
  int base1 = ((h1 >> 5) << 9) + (((h1 >> 3) & 3) << 7) + (h1 & 7);
  int base2 = ((h2 >> 5) << 9) + (((h2 >> 3) & 3) << 7) + (h2 & 7);
#pragma unroll
  for (int l = 0; l < LCH; ++l) {
    float v1 = X32[l * 260 + j];
    float v2 = X32[l * 260 + NPAIR + j];
    float n1 = lr * x1 - li * x2 + v1;
    float n2 = li * x1 + lr * x2 + v2;
    x1 = n1; x2 = n2;
    XA[base1 + l * 8] = (unsigned short)f2bf_bits(x1);
    XA[base2 + l * 8] = (unsigned short)f2bf_bits(x2);
  }
  __syncthreads();

  // --- Y = X @ W_x2y^T via MFMA ---
  const short8* xa = (const short8*)XA;
  const short8* wby = (const short8*)(ws + WS_WBY);
  float4v acc0 = z, acc1 = z;
  int nt0 = wave * 2, nt1 = nt0 + 1;
#pragma unroll
  for (int kk = 0; kk < 8; ++kk) {
    short8 a = xa[kk * 64 + lane];
    acc0 = __builtin_amdgcn_mfma_f32_16x16x32_bf16(a, wby[(nt0 * 8 + kk) * 64 + lane], acc0, 0, 0, 0);
    acc1 = __builtin_amdgcn_mfma_f32_16x16x32_bf16(a, wby[(nt1 * 8 + kk) * 64 + lane], acc1, 0, 0, 0);
  }

  int col = lane & 15;
  float bias0 = bx2y[nt0 * 16 + col];
  float bias1 = bx2y[nt1 * 16 + col];
#pragma unroll
  for (int r = 0; r < 4; ++r) {
    int row = quad * 4 + r;  // t within chunk
    size_t o = ((size_t)(c * LCH + row) * NBAT + b) * NYOUT;
    out[o + nt0 * 16 + col] = acc0[r] + bias0;
    out[o + nt1 * 16 + col] = acc1[r] + bias1;
  }
}

// ---------------------------------------------------------------------------
extern "C" void kernel_launch(void* const* d_in, const int* in_sizes, int n_in,
                              void* d_out, int out_size, void* d_ws, size_t ws_size,
                              hipStream_t stream) {
  (void)in_sizes; (void)n_in; (void)out_size; (void)ws_size;
  const float* y0   = (const float*)d_in[0];
  const float* U    = (const float*)d_in[1];
  const float* lrc  = (const float*)d_in[2];
  const float* lic  = (const float*)d_in[3];
  const float* Bm   = (const float*)d_in[4];
  const float* Wy2x = (const float*)d_in[5];
  const float* by2x = (const float*)d_in[6];
  const float* Wx2y = (const float*)d_in[7];
  const float* bx2y = (const float*)d_in[8];
  float* out = (float*)d_out;
  float* ws  = (float*)d_ws;

  k_prep<<<dim3(NBAT + 3), 256, 0, stream>>>(y0, lrc, lic, Bm, Wy2x, by2x, Wx2y, ws);
  k_phaseA<<<dim3(CCH, NBAT), 128, 0, stream>>>(U, ws);
  k_phaseB<<<dim3(NBAT), 128, 0, stream>>>(ws);
  k_phaseC<<<dim3(CCH, NBAT), 128, 0, stream>>>(U, bx2y, out, ws);
}

// Round 4
// 154.320 us; speedup vs baseline: 1.0864x; 1.0864x over previous
//
#include <hip/hip_runtime.h>
#include <hip/hip_bf16.h>
#include <stdint.h>

// Problem dims
#define T_HRZ 1024
#define NBAT  128
#define NHID  256
#define NPAIR 128
#define NUIN  64
#define NYOUT 64
#define LCH   16   // chunk length
#define CCH   64   // number of chunks

// Workspace layout (float offsets). Total ~4.24M floats = 17 MB.
#define WS_LAM   0         // lr[128], li[128]
#define WS_LAML  256       // lambda^16 r[128], i[128]
#define WS_X0P   512       // x0 pair-interleaved [b][j][2] : 128*128*2
#define WS_WBU   33280     // bf16 B-frags for Bu GEMM [nt16][kk2][lane64][j8]
#define WS_WBY   41472     // bf16 B-frags for Y GEMM  [nt4][kk8][lane64][j8]
#define WS_S     49664     // chunk sums [c][b][j] float2
#define WS_E     2146816   // entry states [c][b][j] float2

// X16 LDS tile: packed bf16 pairs, pitch 264 shorts (132 dwords, 132%32=4)
#define X16_PITCH 264
// XA LDS tile: padded A-frag layout, b-stride 136 shorts, kk-stride 552
#define XA_SB 136
#define XA_SK 552

typedef __attribute__((ext_vector_type(8))) short short8;
typedef __attribute__((ext_vector_type(4))) float float4v;

union Frag { short8 s8; unsigned int u32[4]; };

__device__ __forceinline__ unsigned int f2bf_bits(float x) {
  unsigned int u = __float_as_uint(x);
  return (u + 0x7fffu + ((u >> 16) & 1u)) >> 16;  // RNE
}

__device__ __forceinline__ unsigned int pkbf(float a, float b) {
  __hip_bfloat162 h = __float22bfloat162_rn(make_float2(a, b));
  union { __hip_bfloat162 h2; unsigned int u; } cv; cv.h2 = h; return cv.u;
}

// ---------------------------------------------------------------------------
// K1: prep. grid (NBAT+3) x 256.
// ---------------------------------------------------------------------------
__global__ __launch_bounds__(256) void k_prep(
    const float* __restrict__ y0, const float* __restrict__ lrc,
    const float* __restrict__ lic, const float* __restrict__ Bm,
    const float* __restrict__ Wy2x, const float* __restrict__ by2x,
    const float* __restrict__ Wx2y, float* __restrict__ ws)
{
  int blk = blockIdx.x;
  int h = threadIdx.x;  // 0..255
  if (blk < NBAT) {
    __shared__ float y0s[NYOUT];
    if (h < NYOUT) y0s[h] = y0[blk * NYOUT + h];
    __syncthreads();
    float acc = by2x[h];
    const float* wr = Wy2x + h * NYOUT;
#pragma unroll 16
    for (int k = 0; k < NYOUT; ++k) acc += y0s[k] * wr[k];
    int j = h & (NPAIR - 1);
    int comp = h >> 7;
    ws[WS_X0P + (blk * NPAIR + j) * 2 + comp] = acc;
  } else if (blk == NBAT) {
    if (h < NPAIR) {
      float a  = fabsf(lrc[h]);
      float r  = expf(-a);
      float th = 1.5707963267948966f * lic[h];
      float lr = r * cosf(th);
      float li = r * sinf(th);
      ws[WS_LAM + h]         = lr;
      ws[WS_LAM + NPAIR + h] = li;
      float pr = lr, pi_ = li;
      for (int l = 1; l < LCH; ++l) {
        float nr = pr * lr - pi_ * li;
        float ni = pr * li + pi_ * lr;
        pr = nr; pi_ = ni;
      }
      ws[WS_LAML + h]         = pr;  // lambda^16
      ws[WS_LAML + NPAIR + h] = pi_;
    }
  } else if (blk == NBAT + 1) {
    unsigned short* wbu = (unsigned short*)(ws + WS_WBU);
    for (int idx = h; idx < 16384; idx += 256) {
      int nt   = idx >> 10;
      int kk   = (idx >> 9) & 1;
      int lane = (idx >> 3) & 63;
      int jj   = idx & 7;
      int u  = kk * 32 + (lane >> 4) * 8 + jj;
      int hh = nt * 16 + (lane & 15);
      float a2 = fabsf(lrc[hh & (NPAIR - 1)]);
      float nf = sqrtf(1.f - expf(-2.f * a2));
      wbu[idx] = (unsigned short)f2bf_bits(Bm[hh * NUIN + u] * nf);
    }
  } else {
    unsigned short* wby = (unsigned short*)(ws + WS_WBY);
    for (int idx = h; idx < 16384; idx += 256) {
      int nt   = idx >> 12;
      int kk   = (idx >> 9) & 7;
      int lane = (idx >> 3) & 63;
      int jj   = idx & 7;
      int hh = kk * 32 + (lane >> 4) * 8 + jj;
      int y  = nt * 16 + (lane & 15);
      wby[idx] = (unsigned short)f2bf_bits(Wx2y[y * NHID + hh]);
    }
  }
}

// ---------------------------------------------------------------------------
// K2: phase A. grid (NBAT, CCH) x 128 (2 waves).
// Bu tile via MFMA -> packed-bf16 LDS transpose -> weighted scan -> S.
// ---------------------------------------------------------------------------
__global__ __launch_bounds__(128, 6) void k_phaseA(
    const float* __restrict__ U, float* __restrict__ ws)
{
  int b = blockIdx.x, c = blockIdx.y;
  int tid = threadIdx.x, wave = tid >> 6, lane = tid & 63;
  int l15 = lane & 15, q = lane >> 4;
  __shared__ unsigned short X16[LCH * X16_PITCH];

  // A-frags: U[t=l15][u = kk*32 + q*8 + j]
  const float* urow = U + ((size_t)(c * LCH + l15) * NBAT + b) * NUIN;
  Frag afr[2];
#pragma unroll
  for (int kk = 0; kk < 2; ++kk) {
    int u0 = kk * 32 + q * 8;
    float4 va = *(const float4*)(urow + u0);
    float4 vb = *(const float4*)(urow + u0 + 4);
    afr[kk].u32[0] = pkbf(va.x, va.y);
    afr[kk].u32[1] = pkbf(va.z, va.w);
    afr[kk].u32[2] = pkbf(vb.x, vb.y);
    afr[kk].u32[3] = pkbf(vb.z, vb.w);
  }

  const short8* wbu = (const short8*)(ws + WS_WBU);
  float4v z = {0.f, 0.f, 0.f, 0.f};
  float4v acc[8];
#pragma unroll
  for (int n = 0; n < 8; ++n) acc[n] = z;
#pragma unroll
  for (int n = 0; n < 8; ++n) {
    int nt = wave * 8 + n;
    acc[n] = __builtin_amdgcn_mfma_f32_16x16x32_bf16(afr[0].s8, wbu[(nt * 2 + 0) * 64 + lane], acc[n], 0, 0, 0);
    acc[n] = __builtin_amdgcn_mfma_f32_16x16x32_bf16(afr[1].s8, wbu[(nt * 2 + 1) * 64 + lane], acc[n], 0, 0, 0);
  }

  // C-layout (t=q*4+r, h=(wave*8+n)*16+l15) -> packed pair LDS
#pragma unroll
  for (int n = 0; n < 8; ++n) {
    int hh = (wave * 8 + n) * 16 + l15;
    int off = (hh & 127) * 2 + (hh >> 7);
#pragma unroll
    for (int r = 0; r < 4; ++r)
      X16[(q * 4 + r) * X16_PITCH + off] = (unsigned short)f2bf_bits(acc[n][r]);
  }
  __syncthreads();

  int j = tid;
  float lr = ws[WS_LAM + j], li = ws[WS_LAM + NPAIR + j];
  unsigned int pk[LCH];
#pragma unroll
  for (int l = 0; l < LCH; ++l)
    pk[l] = *(const unsigned int*)(X16 + l * X16_PITCH + j * 2);
  float s1 = 0.f, s2 = 0.f;
#pragma unroll
  for (int l = 0; l < LCH; ++l) {
    float v1 = __uint_as_float(pk[l] << 16);
    float v2 = __uint_as_float(pk[l] & 0xffff0000u);
    float n1 = lr * s1 - li * s2 + v1;
    float n2 = li * s1 + lr * s2 + v2;
    s1 = n1; s2 = n2;
  }
  ((float2*)(ws + WS_S))[((size_t)c * NBAT + b) * NPAIR + j] = make_float2(s1, s2);
}

// ---------------------------------------------------------------------------
// K3: phase B. grid NBAT x 128. 64-step chunk scan, 8-way prefetch.
// ---------------------------------------------------------------------------
__global__ __launch_bounds__(128) void k_phaseB(float* __restrict__ ws)
{
  int b = blockIdx.x, j = threadIdx.x;
  float e1 = ws[WS_X0P + (b * NPAIR + j) * 2 + 0];
  float e2 = ws[WS_X0P + (b * NPAIR + j) * 2 + 1];
  float Lr = ws[WS_LAML + j], Li = ws[WS_LAML + NPAIR + j];
  const float2* sp = (const float2*)(ws + WS_S);
  float2* ep = (float2*)(ws + WS_E);
  const size_t cs = (size_t)NBAT * NPAIR;
  size_t o0 = (size_t)b * NPAIR + j;
  float2 buf[8];
#pragma unroll
  for (int k = 0; k < 8; ++k) buf[k] = sp[k * cs + o0];
  for (int g = 0; g < 8; ++g) {
    float2 nxt[8];
    if (g < 7) {
#pragma unroll
      for (int k = 0; k < 8; ++k) nxt[k] = sp[(size_t)((g + 1) * 8 + k) * cs + o0];
    }
#pragma unroll
    for (int k = 0; k < 8; ++k) {
      ep[(size_t)(g * 8 + k) * cs + o0] = make_float2(e1, e2);
      float n1 = Lr * e1 - Li * e2 + buf[k].x;
      float n2 = Li * e1 + Lr * e2 + buf[k].y;
      e1 = n1; e2 = n2;
    }
    if (g < 7) {
#pragma unroll
      for (int k = 0; k < 8; ++k) buf[k] = nxt[k];
    }
  }
}

// ---------------------------------------------------------------------------
// K4: phase C. grid (NBAT, CCH) x 128 (2 waves).
// Bu recompute via MFMA -> packed LDS -> scan from e[c] -> padded XA ->
// Y-MFMA -> bias epilogue.
// ---------------------------------------------------------------------------
__global__ __launch_bounds__(128, 4) void k_phaseC(
    const float* __restrict__ U, const float* __restrict__ bx2y,
    float* __restrict__ out, float* __restrict__ ws)
{
  int b = blockIdx.x, c = blockIdx.y;
  int tid = threadIdx.x, wave = tid >> 6, lane = tid & 63;
  int l15 = lane & 15, q = lane >> 4;
  __shared__ unsigned short X16[LCH * X16_PITCH];
  __shared__ unsigned short XA[8 * XA_SK];

  // Early loads (hide latency behind the front-end)
  int j = tid;
  float lr = ws[WS_LAM + j], li = ws[WS_LAM + NPAIR + j];
  float2 e = ((const float2*)(ws + WS_E))[((size_t)c * NBAT + b) * NPAIR + j];

  // --- Bu recompute ---
  const float* urow = U + ((size_t)(c * LCH + l15) * NBAT + b) * NUIN;
  Frag afr[2];
#pragma unroll
  for (int kk = 0; kk < 2; ++kk) {
    int u0 = kk * 32 + q * 8;
    float4 va = *(const float4*)(urow + u0);
    float4 vb = *(const float4*)(urow + u0 + 4);
    afr[kk].u32[0] = pkbf(va.x, va.y);
    afr[kk].u32[1] = pkbf(va.z, va.w);
    afr[kk].u32[2] = pkbf(vb.x, vb.y);
    afr[kk].u32[3] = pkbf(vb.z, vb.w);
  }

  const short8* wbu = (const short8*)(ws + WS_WBU);
  float4v z = {0.f, 0.f, 0.f, 0.f};
  {
    float4v acc[8];
#pragma unroll
    for (int n = 0; n < 8; ++n) acc[n] = z;
#pragma unroll
    for (int n = 0; n < 8; ++n) {
      int nt = wave * 8 + n;
      acc[n] = __builtin_amdgcn_mfma_f32_16x16x32_bf16(afr[0].s8, wbu[(nt * 2 + 0) * 64 + lane], acc[n], 0, 0, 0);
      acc[n] = __builtin_amdgcn_mfma_f32_16x16x32_bf16(afr[1].s8, wbu[(nt * 2 + 1) * 64 + lane], acc[n], 0, 0, 0);
    }
#pragma unroll
    for (int n = 0; n < 8; ++n) {
      int hh = (wave * 8 + n) * 16 + l15;
      int off = (hh & 127) * 2 + (hh >> 7);
#pragma unroll
      for (int r = 0; r < 4; ++r)
        X16[(q * 4 + r) * X16_PITCH + off] = (unsigned short)f2bf_bits(acc[n][r]);
    }
  }
  __syncthreads();

  // --- 16-step scan from e[c]; write bf16 X into padded A-frag LDS ---
  unsigned int pk[LCH];
#pragma unroll
  for (int l = 0; l < LCH; ++l)
    pk[l] = *(const unsigned int*)(X16 + l * X16_PITCH + j * 2);

  int base1 = (j >> 5) * XA_SK       + ((j >> 3) & 3) * XA_SB + (j & 7);
  int base2 = ((j >> 5) + 4) * XA_SK + ((j >> 3) & 3) * XA_SB + (j & 7);
  float x1 = e.x, x2 = e.y;
#pragma unroll
  for (int l = 0; l < LCH; ++l) {
    float v1 = __uint_as_float(pk[l] << 16);
    float v2 = __uint_as_float(pk[l] & 0xffff0000u);
    float n1 = lr * x1 - li * x2 + v1;
    float n2 = li * x1 + lr * x2 + v2;
    x1 = n1; x2 = n2;
    XA[base1 + l * 8] = (unsigned short)f2bf_bits(x1);
    XA[base2 + l * 8] = (unsigned short)f2bf_bits(x2);
  }
  __syncthreads();

  // --- Y = X @ W_x2y^T via MFMA ---
  const short8* wby = (const short8*)(ws + WS_WBY);
  float4v acc0 = z, acc1 = z;
  int nt0 = wave * 2, nt1 = nt0 + 1;
#pragma unroll
  for (int kk = 0; kk < 8; ++kk) {
    short8 a = *(const short8*)(XA + kk * XA_SK + q * XA_SB + l15 * 8);
    acc0 = __builtin_amdgcn_mfma_f32_16x16x32_bf16(a, wby[(nt0 * 8 + kk) * 64 + lane], acc0, 0, 0, 0);
    acc1 = __builtin_amdgcn_mfma_f32_16x16x32_bf16(a, wby[(nt1 * 8 + kk) * 64 + lane], acc1, 0, 0, 0);
  }

  float bias0 = bx2y[nt0 * 16 + l15];
  float bias1 = bx2y[nt1 * 16 + l15];
#pragma unroll
  for (int r = 0; r < 4; ++r) {
    int row = q * 4 + r;  // t within chunk
    size_t o = ((size_t)(c * LCH + row) * NBAT + b) * NYOUT;
    out[o + nt0 * 16 + l15] = acc0[r] + bias0;
    out[o + nt1 * 16 + l15] = acc1[r] + bias1;
  }
}

// ---------------------------------------------------------------------------
extern "C" void kernel_launch(void* const* d_in, const int* in_sizes, int n_in,
                              void* d_out, int out_size, void* d_ws, size_t ws_size,
                              hipStream_t stream) {
  (void)in_sizes; (void)n_in; (void)out_size; (void)ws_size;
  const float* y0   = (const float*)d_in[0];
  const float* U    = (const float*)d_in[1];
  const float* lrc  = (const float*)d_in[2];
  const float* lic  = (const float*)d_in[3];
  const float* Bm   = (const float*)d_in[4];
  const float* Wy2x = (const float*)d_in[5];
  const float* by2x = (const float*)d_in[6];
  const float* Wx2y = (const float*)d_in[7];
  const float* bx2y = (const float*)d_in[8];
  float* out = (float*)d_out;
  float* ws  = (float*)d_ws;

  k_prep<<<dim3(NBAT + 3), 256, 0, stream>>>(y0, lrc, lic, Bm, Wy2x, by2x, Wx2y, ws);
  k_phaseA<<<dim3(NBAT, CCH), 128, 0, stream>>>(U, ws);
  k_phaseB<<<dim3(NBAT), 128, 0, stream>>>(ws);
  k_phaseC<<<dim3(NBAT, CCH), 128, 0, stream>>>(U, bx2y, out, ws);
}